// Round 12
// baseline (331.968 us; speedup 1.0000x reference)
//
#include <hip/hip_runtime.h>
#include <hip/hip_fp16.h>

// GAT 2-layer + BN + final linear on MI355X.
// R12: attnagg pass 2 via per-wave LDS staging — lane writes (src,alpha01)
// once (ds_write_b64), loop reads slots with ds_read_b64 (1 LDS op/slot vs
// 2 bpermutes) and runs EXACT per-lane trip counts (no wave-uniform rounding
// waste; avg 17 slots instead of 32). Rest identical to R11 (326us).

#define NEG_SLOPE 0.2f
#define BN_EPS 1e-5f

typedef short bf16x8 __attribute__((ext_vector_type(8)));
typedef float f32x4 __attribute__((ext_vector_type(4)));

static __device__ __forceinline__ unsigned short f2bf(float f) {
    union { float f; unsigned u; } v; v.f = f;
    unsigned r = v.u + 0x7FFF + ((v.u >> 16) & 1);
    return (unsigned short)(r >> 16);
}
static __device__ __forceinline__ float2 bf2x2(unsigned v) {
    union { unsigned u; float f; } a, b;
    a.u = v << 16; b.u = v & 0xffff0000u;
    return make_float2(a.f, b.f);
}
static __device__ __forceinline__ float halfsel(unsigned p, int head) {
    __half2 h = *(__half2*)&p;
    return head ? __high2float(h) : __low2float(h);
}

// ---------------- CSR build ----------------
__global__ void k_rank(const int* __restrict__ ei, int E,
                       int* __restrict__ cnt, unsigned short* __restrict__ rank) {
    int i = blockIdx.x * blockDim.x + threadIdx.x;
    if (i >= E) return;
    int d = ei[E + i];
    rank[i] = (unsigned short)atomicAdd(&cnt[d], 1);
}

__global__ __launch_bounds__(1024) void k_part(const int* __restrict__ cnt, int Nn,
                                               int* __restrict__ part) {
    __shared__ int ws[16];
    int t = threadIdx.x, lane = t & 63, w = t >> 6;
    int i = blockIdx.x * 1024 + t;
    int v = (i < Nn) ? cnt[i] + 1 : 0;        // +1: self-loop per node
    #pragma unroll
    for (int off = 32; off; off >>= 1) v += __shfl_xor(v, off);
    if (lane == 0) ws[w] = v;
    __syncthreads();
    if (t < 16) {
        int s = ws[t];
        #pragma unroll
        for (int off = 8; off; off >>= 1) s += __shfl_xor(s, off);
        if (t == 0) part[blockIdx.x] = s;
    }
}

__global__ __launch_bounds__(1024) void k_scan2(const int* __restrict__ cnt, int Nn, int nb,
                                                const int* __restrict__ part,
                                                int* __restrict__ rowptr) {
    __shared__ int wsum[16];
    __shared__ int s_base, s_total;
    int t = threadIdx.x, lane = t & 63, w = t >> 6;
    int b = blockIdx.x;
    if (w == 0) {
        int base = 0, total = 0;
        for (int ch = 0; ch < nb; ch += 64) {
            int j = ch + lane;
            int v = (j < nb) ? part[j] : 0;
            total += v;
            base += (j < b) ? v : 0;
        }
        #pragma unroll
        for (int off = 32; off; off >>= 1) {
            base += __shfl_xor(base, off);
            total += __shfl_xor(total, off);
        }
        if (lane == 0) { s_base = base; s_total = total; }
    }
    int i = b * 1024 + t;
    int v = (i < Nn) ? cnt[i] + 1 : 0;        // +1: self-loop per node
    int x = v;
    #pragma unroll
    for (int off = 1; off < 64; off <<= 1) {
        int y = __shfl_up(x, off);
        if (lane >= off) x += y;
    }
    if (lane == 63) wsum[w] = x;
    __syncthreads();
    if (w == 0) {
        int val = (lane < 16) ? wsum[lane] : 0;
        int xs = val;
        #pragma unroll
        for (int off = 1; off < 16; off <<= 1) {
            int y = __shfl_up(xs, off);
            if (lane >= off) xs += y;
        }
        if (lane < 16) wsum[lane] = xs - val;
    }
    __syncthreads();
    if (i < Nn) rowptr[i] = s_base + wsum[w] + (x - v);
    if (b == gridDim.x - 1 && t == 0) rowptr[Nn] = s_total;
}

__global__ void k_fill2(const int* __restrict__ ei, const unsigned short* __restrict__ rank,
                        const int* __restrict__ rowptr, int E, int Nn,
                        unsigned short* __restrict__ ssrc) {
    int i = blockIdx.x * blockDim.x + threadIdx.x;
    if (i < E) {
        int s = ei[i], d = ei[E + i];
        ssrc[rowptr[d] + 1 + (int)rank[i]] = (unsigned short)s;
    } else if (i < E + Nn) {
        int d = i - E;
        ssrc[rowptr[d]] = (unsigned short)d;   // self-loop slot 0, coalesced
    }
}

// ---------------- BatchNorm stats: vectorized streaming ----------------
template <int C>
__global__ __launch_bounds__(256) void k_bnstat2(const float* __restrict__ x, int M,
                                                 int rowsPerBlock, float* __restrict__ sums) {
    constexpr int TPR = C / 4;
    constexpr int RS  = 256 / TPR;
    __shared__ float red[4][2 * C];
    const int t = threadIdx.x;
    const int cg = t % TPR, rg = t / TPR, w = t >> 6, lane = t & 63;
    int r0 = blockIdx.x * rowsPerBlock + rg;
    int r1 = min(M, blockIdx.x * rowsPerBlock + rowsPerBlock);
    float4 s = make_float4(0, 0, 0, 0), q = make_float4(0, 0, 0, 0);
    #pragma unroll 4
    for (int r = r0; r < r1; r += RS) {
        float4 v = *(const float4*)&x[(size_t)r * C + cg * 4];
        s.x += v.x; s.y += v.y; s.z += v.z; s.w += v.w;
        q.x += v.x * v.x; q.y += v.y * v.y; q.z += v.z * v.z; q.w += v.w * v.w;
    }
    #pragma unroll
    for (int off = TPR; off < 64; off <<= 1) {
        s.x += __shfl_xor(s.x, off); s.y += __shfl_xor(s.y, off);
        s.z += __shfl_xor(s.z, off); s.w += __shfl_xor(s.w, off);
        q.x += __shfl_xor(q.x, off); q.y += __shfl_xor(q.y, off);
        q.z += __shfl_xor(q.z, off); q.w += __shfl_xor(q.w, off);
    }
    if (lane < TPR) {
        *(float4*)&red[w][cg * 4] = s;
        *(float4*)&red[w][C + cg * 4] = q;
    }
    __syncthreads();
    for (int idx = t; idx < 2 * C; idx += 256) {
        float tot = red[0][idx] + red[1][idx] + red[2][idx] + red[3][idx];
        atomicAdd(&sums[idx], tot);
    }
}

__global__ void k_bnfin(const float* __restrict__ sums, int M, int C,
                        const float* __restrict__ g, const float* __restrict__ b,
                        float* __restrict__ st) {
    int c = threadIdx.x;
    if (c < C) {
        float mu = sums[c] / (float)M;
        float var = sums[C + c] / (float)M - mu * mu;
        float s = g[c] * rsqrtf(var + BN_EPS);
        st[c] = s;
        st[C + c] = b[c] - mu * s;
    }
}

// ---------------- W^T bf16 (both layers in one launch) ----------------
__global__ __launch_bounds__(256) void k_wt2(const float* __restrict__ W1, const float* __restrict__ W2,
                                             unsigned short* __restrict__ wt1, unsigned short* __restrict__ wt2) {
    int idx = blockIdx.x * 256 + threadIdx.x;
    if (idx >= 128 * 128) return;
    int n = idx >> 7, k = idx & 127;
    wt1[idx] = f2bf(W1[k * 128 + n]);
    wt2[idx] = f2bf(W2[k * 128 + n]);
}

// ---------------- MFMA GEMM [M,128]@[128,128], BN affine(+ELU)+cvt fused in A staging ----------------
__global__ __launch_bounds__(256) void k_mfma(
    const float* __restrict__ A, const unsigned short* __restrict__ wt,
    const float* __restrict__ stp, int elu,
    const float* __restrict__ asrc, const float* __restrict__ adst, int M,
    unsigned short* __restrict__ hb, float* __restrict__ als, float* __restrict__ ald) {
    __shared__ unsigned short As[64 * 136];
    __shared__ unsigned short Bs[128 * 136];
    const int t = threadIdx.x;
    const int w = t >> 6, lane = t & 63;
    const int c = lane & 15, q = lane >> 4;
    const int row0 = blockIdx.x * 64;

    #pragma unroll
    for (int i = 0; i < 8; i++) {
        int idx = t + i * 256;
        int r = idx >> 5, ch4 = idx & 31;
        int gr = row0 + r;
        float4 v = make_float4(0, 0, 0, 0);
        if (gr < M) {
            v = *(const float4*)&A[(size_t)gr * 128 + ch4 * 4];
            float4 sc = *(const float4*)&stp[ch4 * 4];
            float4 sh = *(const float4*)&stp[128 + ch4 * 4];
            v.x = v.x * sc.x + sh.x; v.y = v.y * sc.y + sh.y;
            v.z = v.z * sc.z + sh.z; v.w = v.w * sc.w + sh.w;
            if (elu) {
                v.x = v.x > 0.f ? v.x : expm1f(v.x);
                v.y = v.y > 0.f ? v.y : expm1f(v.y);
                v.z = v.z > 0.f ? v.z : expm1f(v.z);
                v.w = v.w > 0.f ? v.w : expm1f(v.w);
            }
        }
        unsigned p0 = ((unsigned)f2bf(v.y) << 16) | f2bf(v.x);
        unsigned p1 = ((unsigned)f2bf(v.w) << 16) | f2bf(v.z);
        *(uint2*)&As[r * 136 + ch4 * 4] = make_uint2(p0, p1);
    }
    #pragma unroll
    for (int i = 0; i < 8; i++) {
        int idx = t + i * 256;
        int r = idx >> 4, ch = idx & 15;
        *(uint4*)&Bs[r * 136 + ch * 8] = *(const uint4*)&wt[(size_t)r * 128 + ch * 8];
    }
    __syncthreads();

    f32x4 acc[8] = {};
    #pragma unroll
    for (int ks = 0; ks < 4; ks++) {
        bf16x8 a = *(bf16x8*)&As[(w * 16 + c) * 136 + (ks * 4 + q) * 8];
        #pragma unroll
        for (int tl = 0; tl < 8; tl++) {
            bf16x8 b = *(bf16x8*)&Bs[(tl * 16 + c) * 136 + (ks * 4 + q) * 8];
            acc[tl] = __builtin_amdgcn_mfma_f32_16x16x32_bf16(a, b, acc[tl], 0, 0, 0);
        }
    }

    #pragma unroll
    for (int reg = 0; reg < 4; reg++) {
        int grow = row0 + w * 16 + q * 4 + reg;
        if (grow < M) {
            #pragma unroll
            for (int tl = 0; tl < 8; tl++)
                hb[(size_t)grow * 128 + tl * 16 + c] = f2bf(acc[tl][reg]);
        }
    }

    float as_[8], ad_[8];
    #pragma unroll
    for (int tl = 0; tl < 8; tl++) { as_[tl] = asrc[tl * 16 + c]; ad_[tl] = adst[tl * 16 + c]; }
    #pragma unroll
    for (int reg = 0; reg < 4; reg++) {
        float s0 = 0.f, s1 = 0.f, d0 = 0.f, d1 = 0.f;
        #pragma unroll
        for (int tl = 0; tl < 4; tl++) { s0 += acc[tl][reg] * as_[tl]; d0 += acc[tl][reg] * ad_[tl]; }
        #pragma unroll
        for (int tl = 4; tl < 8; tl++) { s1 += acc[tl][reg] * as_[tl]; d1 += acc[tl][reg] * ad_[tl]; }
        #pragma unroll
        for (int off = 1; off < 16; off <<= 1) {
            s0 += __shfl_xor(s0, off); s1 += __shfl_xor(s1, off);
            d0 += __shfl_xor(d0, off); d1 += __shfl_xor(d1, off);
        }
        int grow = row0 + w * 16 + q * 4 + reg;
        if (c == 0 && grow < M) {
            *(float2*)&als[(size_t)grow * 2] = make_float2(s0, s1);
            *(float2*)&ald[(size_t)grow * 2] = make_float2(d0, d1);
        }
    }
}

// ---------------- fused softmax + aggregation: wave per dst node ----------------
static __device__ __forceinline__ void acc8(float* acc, uint4 v, float a) {
    float2 p;
    p = bf2x2(v.x); acc[0] += a * p.x; acc[1] += a * p.y;
    p = bf2x2(v.y); acc[2] += a * p.x; acc[3] += a * p.y;
    p = bf2x2(v.z); acc[4] += a * p.x; acc[5] += a * p.y;
    p = bf2x2(v.w); acc[6] += a * p.x; acc[7] += a * p.y;
}

template <int MEAN>
static __device__ __forceinline__ void attnagg(
    const int* __restrict__ rowptr, const unsigned short* __restrict__ ssrc,
    const float* __restrict__ als, const float* __restrict__ ald,
    float* __restrict__ alpha, const unsigned short* __restrict__ hb,
    const float* __restrict__ bias, int Nn, float* __restrict__ out) {
    __shared__ uint2 sdata[4][64];               // per-wave (src, alpha-fp16x2)
    int gw = (blockIdx.x * blockDim.x + threadIdx.x) >> 6;
    if (gw >= Nn) return;
    int wv = (threadIdx.x >> 6) & 3;
    int lane = threadIdx.x & 63;
    int sub = lane >> 4, c = lane & 15, head = c >> 3;
    int beg = rowptr[gw], end = rowptr[gw + 1];
    int deg = end - beg;
    float2 dv = *(const float2*)&ald[(size_t)gw * 2];
    float acc[8] = {};

    if (deg <= 64) {
        bool on = lane < deg;
        int eidx = beg + (on ? lane : 0);
        int sreg = (int)ssrc[eidx];
        float2 av = *(const float2*)&als[(size_t)sreg * 2];
        float v0 = av.x + dv.x; v0 = v0 > 0.f ? v0 : NEG_SLOPE * v0;
        float v1 = av.y + dv.y; v1 = v1 > 0.f ? v1 : NEG_SLOPE * v1;
        // post-BN logits: |v| << 88, exp safe without max-subtraction
        float p0 = on ? __expf(v0) : 0.f;
        float p1 = on ? __expf(v1) : 0.f;
        float t0 = p0, t1 = p1;
        #pragma unroll
        for (int off = 32; off; off >>= 1) {
            t0 += __shfl_xor(t0, off);
            t1 += __shfl_xor(t1, off);
        }
        __half2 hpk = __floats2half2_rn(p0 / t0, p1 / t1);
        unsigned pk = *(unsigned*)&hpk;

        // stage (src, alpha01) once; same-wave RAW -> no barrier needed
        sdata[wv][lane] = make_uint2((unsigned)sreg, pk);

        // pass 2: exact per-lane trip count, ds_read_b64 per slot, 4-deep MLP
        int j = sub;
        for (; j + 12 < deg; j += 16) {
            uint2 d0 = sdata[wv][j];
            uint2 d1 = sdata[wv][j + 4];
            uint2 d2 = sdata[wv][j + 8];
            uint2 d3 = sdata[wv][j + 12];
            uint4 v0g = *(const uint4*)&hb[(size_t)d0.x * 128 + c * 8];
            uint4 v1g = *(const uint4*)&hb[(size_t)d1.x * 128 + c * 8];
            uint4 v2g = *(const uint4*)&hb[(size_t)d2.x * 128 + c * 8];
            uint4 v3g = *(const uint4*)&hb[(size_t)d3.x * 128 + c * 8];
            acc8(acc, v0g, halfsel(d0.y, head));
            acc8(acc, v1g, halfsel(d1.y, head));
            acc8(acc, v2g, halfsel(d2.y, head));
            acc8(acc, v3g, halfsel(d3.y, head));
        }
        for (; j < deg; j += 4) {
            uint2 d = sdata[wv][j];
            uint4 v = *(const uint4*)&hb[(size_t)d.x * 128 + c * 8];
            acc8(acc, v, halfsel(d.y, head));
        }
    } else {
        // fallback (deg > 64): alpha via global buffer, with max-subtract
        float d0 = dv.x, d1 = dv.y;
        float m0 = -1e30f, m1 = -1e30f;
        for (int e = beg + lane; e < end; e += 64) {
            int s = (int)ssrc[e];
            float v0 = als[s * 2] + d0;     v0 = v0 > 0.f ? v0 : NEG_SLOPE * v0;
            float v1 = als[s * 2 + 1] + d1; v1 = v1 > 0.f ? v1 : NEG_SLOPE * v1;
            m0 = fmaxf(m0, v0); m1 = fmaxf(m1, v1);
        }
        #pragma unroll
        for (int off = 32; off; off >>= 1) {
            m0 = fmaxf(m0, __shfl_xor(m0, off));
            m1 = fmaxf(m1, __shfl_xor(m1, off));
        }
        float t0 = 0.f, t1 = 0.f;
        for (int e = beg + lane; e < end; e += 64) {
            int s = (int)ssrc[e];
            float v0 = als[s * 2] + d0;     v0 = v0 > 0.f ? v0 : NEG_SLOPE * v0;
            float v1 = als[s * 2 + 1] + d1; v1 = v1 > 0.f ? v1 : NEG_SLOPE * v1;
            float p0 = __expf(v0 - m0), p1 = __expf(v1 - m1);
            alpha[e * 2] = p0; alpha[e * 2 + 1] = p1;
            t0 += p0; t1 += p1;
        }
        #pragma unroll
        for (int off = 32; off; off >>= 1) {
            t0 += __shfl_xor(t0, off);
            t1 += __shfl_xor(t1, off);
        }
        float i0 = 1.f / t0, i1 = 1.f / t1;
        for (int e = beg + sub; e < end; e += 4) {
            int s = (int)ssrc[e];
            float a = (head ? alpha[(size_t)e * 2 + 1] * i1 : alpha[(size_t)e * 2] * i0);
            uint4 v = *(const uint4*)&hb[(size_t)s * 128 + c * 8];
            acc8(acc, v, a);
        }
    }

    #pragma unroll
    for (int j2 = 0; j2 < 8; j2++) {
        acc[j2] += __shfl_xor(acc[j2], 16);
        acc[j2] += __shfl_xor(acc[j2], 32);
        if (MEAN) acc[j2] += __shfl_xor(acc[j2], 8);
    }
    if (MEAN) {
        if (sub == 0 && c < 8) {
            float4 b0 = *(const float4*)&bias[c * 8];
            float4 b1 = *(const float4*)&bias[c * 8 + 4];
            float4 o0 = make_float4(0.5f * acc[0] + b0.x, 0.5f * acc[1] + b0.y, 0.5f * acc[2] + b0.z, 0.5f * acc[3] + b0.w);
            float4 o1 = make_float4(0.5f * acc[4] + b1.x, 0.5f * acc[5] + b1.y, 0.5f * acc[6] + b1.z, 0.5f * acc[7] + b1.w);
            *(float4*)&out[(size_t)gw * 64 + c * 8] = o0;
            *(float4*)&out[(size_t)gw * 64 + c * 8 + 4] = o1;
        }
    } else {
        if (sub == 0) {
            float4 b0 = *(const float4*)&bias[c * 8];
            float4 b1 = *(const float4*)&bias[c * 8 + 4];
            float4 o0 = make_float4(acc[0] + b0.x, acc[1] + b0.y, acc[2] + b0.z, acc[3] + b0.w);
            float4 o1 = make_float4(acc[4] + b1.x, acc[5] + b1.y, acc[6] + b1.z, acc[7] + b1.w);
            *(float4*)&out[(size_t)gw * 128 + c * 8] = o0;
            *(float4*)&out[(size_t)gw * 128 + c * 8 + 4] = o1;
        }
    }
}

__global__ __launch_bounds__(256) void k_attnagg1(const int* __restrict__ rowptr, const unsigned short* __restrict__ ssrc,
                                                  const float* __restrict__ als, const float* __restrict__ ald,
                                                  float* __restrict__ alpha, const unsigned short* __restrict__ hb,
                                                  const float* __restrict__ bias, int Nn, float* __restrict__ out) {
    attnagg<0>(rowptr, ssrc, als, ald, alpha, hb, bias, Nn, out);
}

__global__ __launch_bounds__(256) void k_attnagg2(const int* __restrict__ rowptr, const unsigned short* __restrict__ ssrc,
                                                  const float* __restrict__ als, const float* __restrict__ ald,
                                                  float* __restrict__ alpha, const unsigned short* __restrict__ hb,
                                                  const float* __restrict__ bias, int Nn, float* __restrict__ out) {
    attnagg<1>(rowptr, ssrc, als, ald, alpha, hb, bias, Nn, out);
}

// ---------------- final GEMM [M,64] @ [64,40] + bias, BN affine + ELU fused on A ----------------
__global__ __launch_bounds__(128) void k_gemmf(const float* __restrict__ A, const float* __restrict__ Wf,
                                               const float* __restrict__ bf, const float* __restrict__ st,
                                               int M, float* __restrict__ out) {
    __shared__ float As[128 * 65];
    __shared__ float Bs[64 * 40];
    int t = threadIdx.x;
    int row0 = blockIdx.x * 128;
    for (int i = t; i < 64 * 40; i += 128) Bs[i] = Wf[i];
    for (int i = t; i < 128 * 64; i += 128) {
        int r = i >> 6, k = i & 63;
        int gr = row0 + r;
        float v = 0.f;
        if (gr < M) {
            v = A[(size_t)gr * 64 + k] * st[k] + st[64 + k];
            v = v > 0.f ? v : expm1f(v);
        }
        As[r * 65 + k] = v;
    }
    __syncthreads();
    int cg = t & 3, rg = t >> 2;
    float acc[4][10] = {};
    for (int k = 0; k < 64; k++) {
        float b[10];
        #pragma unroll
        for (int j = 0; j < 10; j++) b[j] = Bs[k * 40 + cg * 10 + j];
        #pragma unroll
        for (int r = 0; r < 4; r++) {
            float a = As[(rg * 4 + r) * 65 + k];
            #pragma unroll
            for (int j = 0; j < 10; j++) acc[r][j] += a * b[j];
        }
    }
    for (int r = 0; r < 4; r++) {
        int gr = row0 + rg * 4 + r;
        if (gr < M) {
            #pragma unroll
            for (int j = 0; j < 10; j++) out[(size_t)gr * 40 + cg * 10 + j] = acc[r][j] + bf[cg * 10 + j];
        }
    }
}

extern "C" void kernel_launch(void* const* d_in, const int* in_sizes, int n_in,
                              void* d_out, int out_size, void* d_ws, size_t ws_size,
                              hipStream_t stream) {
    const float* x     = (const float*)d_in[0];
    const int*   ei    = (const int*)d_in[1];
    const float* bn0_g = (const float*)d_in[2];
    const float* bn0_b = (const float*)d_in[3];
    const float* W1    = (const float*)d_in[4];
    const float* a1s   = (const float*)d_in[5];
    const float* a1d   = (const float*)d_in[6];
    const float* b1    = (const float*)d_in[7];
    const float* bn1_g = (const float*)d_in[8];
    const float* bn1_b = (const float*)d_in[9];
    const float* W2    = (const float*)d_in[10];
    const float* a2s   = (const float*)d_in[11];
    const float* a2d   = (const float*)d_in[12];
    const float* b2    = (const float*)d_in[13];
    const float* bn2_g = (const float*)d_in[14];
    const float* bn2_b = (const float*)d_in[15];
    const float* Wf    = (const float*)d_in[16];
    const float* bf    = (const float*)d_in[17];
    float* out = (float*)d_out;

    const int N  = in_sizes[0] / 128;   // 50000 < 65536: u16 ssrc/rank valid
    const int E  = in_sizes[1] / 2;
    const int ET = E + N;

    char* ws = (char*)d_ws;
    size_t off = 0;
    auto alloc = [&](size_t bytes) -> char* {
        char* p = ws + off;
        off = (off + bytes + 255) & ~(size_t)255;
        return p;
    };
    int*   cnt    = (int*)alloc((size_t)N * 4);
    int*   rowptr = (int*)alloc((size_t)(N + 1) * 4);
    unsigned short* ssrc = (unsigned short*)alloc((size_t)ET * 2);
    float* abuf   = (float*)alloc((size_t)N * 128 * 4);
    unsigned short* hb  = (unsigned short*)alloc((size_t)N * 128 * 2);
    unsigned short* wt1 = (unsigned short*)alloc((size_t)128 * 128 * 2);
    unsigned short* wt2 = (unsigned short*)alloc((size_t)128 * 128 * 2);
    float* alpha  = (float*)alloc((size_t)ET * 2 * 4);   // deg>64 fallback only
    float* als    = (float*)alloc((size_t)N * 2 * 4);
    float* ald    = (float*)alloc((size_t)N * 2 * 4);
    int*   part   = (int*)alloc(1024 * 4);
    float* sums   = (float*)alloc(640 * 4);      // BN0:0, BN1:+256, BN2:+512
    float* st     = (float*)alloc(256 * 4);
    // alias: rank (u16) lives k_rank -> k_fill2; hb first written at k_mfma
    unsigned short* rank = (unsigned short*)hb;

    const int tb = 256;
    const int rgrid = (E + tb - 1) / tb;
    const int fgrid = (ET + tb - 1) / tb;
    const int wgrid = ((size_t)N * 64 + tb - 1) / tb;
    const int ggrid = (N + 63) / 64;
    const int nscan = (N + 1023) / 1024;
    const int bgrid = (N + 255) / 256;

    // CSR build
    hipMemsetAsync(cnt, 0, (size_t)N * 4, stream);
    hipMemsetAsync(sums, 0, 640 * 4, stream);
    k_rank<<<rgrid, tb, 0, stream>>>(ei, E, cnt, rank);
    k_part<<<nscan, 1024, 0, stream>>>(cnt, N, part);
    k_scan2<<<nscan, 1024, 0, stream>>>(cnt, N, nscan, part, rowptr);
    k_fill2<<<fgrid, tb, 0, stream>>>(ei, rank, rowptr, E, N, ssrc);

    // weights
    k_wt2<<<64, tb, 0, stream>>>(W1, W2, wt1, wt2);

    // BN0
    k_bnstat2<128><<<bgrid, 256, 0, stream>>>(x, N, 256, sums);
    k_bnfin<<<1, 128, 0, stream>>>(sums, N, 128, bn0_g, bn0_b, st);

    // layer 1 (BN0 affine fused into GEMM A staging)
    k_mfma<<<ggrid, tb, 0, stream>>>(x, wt1, st, 0, a1s, a1d, N, hb, als, ald);
    k_attnagg1<<<wgrid, tb, 0, stream>>>(rowptr, ssrc, als, ald, alpha, hb, b1, N, abuf);

    // BN1
    k_bnstat2<128><<<bgrid, 256, 0, stream>>>(abuf, N, 256, sums + 256);
    k_bnfin<<<1, 128, 0, stream>>>(sums + 256, N, 128, bn1_g, bn1_b, st);

    // layer 2 (BN1 affine + ELU fused into GEMM A staging)
    k_mfma<<<ggrid, tb, 0, stream>>>(abuf, wt2, st, 1, a2s, a2d, N, hb, als, ald);
    k_attnagg2<<<wgrid, tb, 0, stream>>>(rowptr, ssrc, als, ald, alpha, hb, b2, N, abuf);

    // BN2
    k_bnstat2<64><<<bgrid, 256, 0, stream>>>(abuf, N, 256, sums + 512);
    k_bnfin<<<1, 64, 0, stream>>>(sums + 512, N, 64, bn2_g, bn2_b, st);

    // final linear
    k_gemmf<<<(N + 127) / 128, 128, 0, stream>>>(abuf, Wf, bf, st, N, out);
}

// Round 13
// 325.109 us; speedup vs baseline: 1.0211x; 1.0211x over previous
//
#include <hip/hip_runtime.h>
#include <hip/hip_fp16.h>

// GAT 2-layer + BN + final linear on MI355X.
// R13: revert R12's LDS staging (divergent trips + ds_read latency regressed).
// Back to R11's bpermute pass-2, but with a wave-uniform 2-group tail after
// the 4-group batches: deg~17 now executes 24 slots instead of 32 (-25%
// pass-2 work), no divergence, shfls always full-wave.

#define NEG_SLOPE 0.2f
#define BN_EPS 1e-5f

typedef short bf16x8 __attribute__((ext_vector_type(8)));
typedef float f32x4 __attribute__((ext_vector_type(4)));

static __device__ __forceinline__ unsigned short f2bf(float f) {
    union { float f; unsigned u; } v; v.f = f;
    unsigned r = v.u + 0x7FFF + ((v.u >> 16) & 1);
    return (unsigned short)(r >> 16);
}
static __device__ __forceinline__ float2 bf2x2(unsigned v) {
    union { unsigned u; float f; } a, b;
    a.u = v << 16; b.u = v & 0xffff0000u;
    return make_float2(a.f, b.f);
}
static __device__ __forceinline__ float halfsel(unsigned p, int head) {
    __half2 h = *(__half2*)&p;
    return head ? __high2float(h) : __low2float(h);
}

// ---------------- CSR build ----------------
__global__ void k_rank(const int* __restrict__ ei, int E,
                       int* __restrict__ cnt, unsigned short* __restrict__ rank) {
    int i = blockIdx.x * blockDim.x + threadIdx.x;
    if (i >= E) return;
    int d = ei[E + i];
    rank[i] = (unsigned short)atomicAdd(&cnt[d], 1);
}

__global__ __launch_bounds__(1024) void k_part(const int* __restrict__ cnt, int Nn,
                                               int* __restrict__ part) {
    __shared__ int ws[16];
    int t = threadIdx.x, lane = t & 63, w = t >> 6;
    int i = blockIdx.x * 1024 + t;
    int v = (i < Nn) ? cnt[i] + 1 : 0;        // +1: self-loop per node
    #pragma unroll
    for (int off = 32; off; off >>= 1) v += __shfl_xor(v, off);
    if (lane == 0) ws[w] = v;
    __syncthreads();
    if (t < 16) {
        int s = ws[t];
        #pragma unroll
        for (int off = 8; off; off >>= 1) s += __shfl_xor(s, off);
        if (t == 0) part[blockIdx.x] = s;
    }
}

__global__ __launch_bounds__(1024) void k_scan2(const int* __restrict__ cnt, int Nn, int nb,
                                                const int* __restrict__ part,
                                                int* __restrict__ rowptr) {
    __shared__ int wsum[16];
    __shared__ int s_base, s_total;
    int t = threadIdx.x, lane = t & 63, w = t >> 6;
    int b = blockIdx.x;
    if (w == 0) {
        int base = 0, total = 0;
        for (int ch = 0; ch < nb; ch += 64) {
            int j = ch + lane;
            int v = (j < nb) ? part[j] : 0;
            total += v;
            base += (j < b) ? v : 0;
        }
        #pragma unroll
        for (int off = 32; off; off >>= 1) {
            base += __shfl_xor(base, off);
            total += __shfl_xor(total, off);
        }
        if (lane == 0) { s_base = base; s_total = total; }
    }
    int i = b * 1024 + t;
    int v = (i < Nn) ? cnt[i] + 1 : 0;        // +1: self-loop per node
    int x = v;
    #pragma unroll
    for (int off = 1; off < 64; off <<= 1) {
        int y = __shfl_up(x, off);
        if (lane >= off) x += y;
    }
    if (lane == 63) wsum[w] = x;
    __syncthreads();
    if (w == 0) {
        int val = (lane < 16) ? wsum[lane] : 0;
        int xs = val;
        #pragma unroll
        for (int off = 1; off < 16; off <<= 1) {
            int y = __shfl_up(xs, off);
            if (lane >= off) xs += y;
        }
        if (lane < 16) wsum[lane] = xs - val;
    }
    __syncthreads();
    if (i < Nn) rowptr[i] = s_base + wsum[w] + (x - v);
    if (b == gridDim.x - 1 && t == 0) rowptr[Nn] = s_total;
}

__global__ void k_fill2(const int* __restrict__ ei, const unsigned short* __restrict__ rank,
                        const int* __restrict__ rowptr, int E, int Nn,
                        unsigned short* __restrict__ ssrc) {
    int i = blockIdx.x * blockDim.x + threadIdx.x;
    if (i < E) {
        int s = ei[i], d = ei[E + i];
        ssrc[rowptr[d] + 1 + (int)rank[i]] = (unsigned short)s;
    } else if (i < E + Nn) {
        int d = i - E;
        ssrc[rowptr[d]] = (unsigned short)d;   // self-loop slot 0, coalesced
    }
}

// ---------------- BatchNorm stats: vectorized streaming ----------------
template <int C>
__global__ __launch_bounds__(256) void k_bnstat2(const float* __restrict__ x, int M,
                                                 int rowsPerBlock, float* __restrict__ sums) {
    constexpr int TPR = C / 4;
    constexpr int RS  = 256 / TPR;
    __shared__ float red[4][2 * C];
    const int t = threadIdx.x;
    const int cg = t % TPR, rg = t / TPR, w = t >> 6, lane = t & 63;
    int r0 = blockIdx.x * rowsPerBlock + rg;
    int r1 = min(M, blockIdx.x * rowsPerBlock + rowsPerBlock);
    float4 s = make_float4(0, 0, 0, 0), q = make_float4(0, 0, 0, 0);
    #pragma unroll 4
    for (int r = r0; r < r1; r += RS) {
        float4 v = *(const float4*)&x[(size_t)r * C + cg * 4];
        s.x += v.x; s.y += v.y; s.z += v.z; s.w += v.w;
        q.x += v.x * v.x; q.y += v.y * v.y; q.z += v.z * v.z; q.w += v.w * v.w;
    }
    #pragma unroll
    for (int off = TPR; off < 64; off <<= 1) {
        s.x += __shfl_xor(s.x, off); s.y += __shfl_xor(s.y, off);
        s.z += __shfl_xor(s.z, off); s.w += __shfl_xor(s.w, off);
        q.x += __shfl_xor(q.x, off); q.y += __shfl_xor(q.y, off);
        q.z += __shfl_xor(q.z, off); q.w += __shfl_xor(q.w, off);
    }
    if (lane < TPR) {
        *(float4*)&red[w][cg * 4] = s;
        *(float4*)&red[w][C + cg * 4] = q;
    }
    __syncthreads();
    for (int idx = t; idx < 2 * C; idx += 256) {
        float tot = red[0][idx] + red[1][idx] + red[2][idx] + red[3][idx];
        atomicAdd(&sums[idx], tot);
    }
}

__global__ void k_bnfin(const float* __restrict__ sums, int M, int C,
                        const float* __restrict__ g, const float* __restrict__ b,
                        float* __restrict__ st) {
    int c = threadIdx.x;
    if (c < C) {
        float mu = sums[c] / (float)M;
        float var = sums[C + c] / (float)M - mu * mu;
        float s = g[c] * rsqrtf(var + BN_EPS);
        st[c] = s;
        st[C + c] = b[c] - mu * s;
    }
}

// ---------------- W^T bf16 (both layers in one launch) ----------------
__global__ __launch_bounds__(256) void k_wt2(const float* __restrict__ W1, const float* __restrict__ W2,
                                             unsigned short* __restrict__ wt1, unsigned short* __restrict__ wt2) {
    int idx = blockIdx.x * 256 + threadIdx.x;
    if (idx >= 128 * 128) return;
    int n = idx >> 7, k = idx & 127;
    wt1[idx] = f2bf(W1[k * 128 + n]);
    wt2[idx] = f2bf(W2[k * 128 + n]);
}

// ---------------- MFMA GEMM [M,128]@[128,128], BN affine(+ELU)+cvt fused in A staging ----------------
__global__ __launch_bounds__(256) void k_mfma(
    const float* __restrict__ A, const unsigned short* __restrict__ wt,
    const float* __restrict__ stp, int elu,
    const float* __restrict__ asrc, const float* __restrict__ adst, int M,
    unsigned short* __restrict__ hb, float* __restrict__ als, float* __restrict__ ald) {
    __shared__ unsigned short As[64 * 136];
    __shared__ unsigned short Bs[128 * 136];
    const int t = threadIdx.x;
    const int w = t >> 6, lane = t & 63;
    const int c = lane & 15, q = lane >> 4;
    const int row0 = blockIdx.x * 64;

    #pragma unroll
    for (int i = 0; i < 8; i++) {
        int idx = t + i * 256;
        int r = idx >> 5, ch4 = idx & 31;
        int gr = row0 + r;
        float4 v = make_float4(0, 0, 0, 0);
        if (gr < M) {
            v = *(const float4*)&A[(size_t)gr * 128 + ch4 * 4];
            float4 sc = *(const float4*)&stp[ch4 * 4];
            float4 sh = *(const float4*)&stp[128 + ch4 * 4];
            v.x = v.x * sc.x + sh.x; v.y = v.y * sc.y + sh.y;
            v.z = v.z * sc.z + sh.z; v.w = v.w * sc.w + sh.w;
            if (elu) {
                v.x = v.x > 0.f ? v.x : expm1f(v.x);
                v.y = v.y > 0.f ? v.y : expm1f(v.y);
                v.z = v.z > 0.f ? v.z : expm1f(v.z);
                v.w = v.w > 0.f ? v.w : expm1f(v.w);
            }
        }
        unsigned p0 = ((unsigned)f2bf(v.y) << 16) | f2bf(v.x);
        unsigned p1 = ((unsigned)f2bf(v.w) << 16) | f2bf(v.z);
        *(uint2*)&As[r * 136 + ch4 * 4] = make_uint2(p0, p1);
    }
    #pragma unroll
    for (int i = 0; i < 8; i++) {
        int idx = t + i * 256;
        int r = idx >> 4, ch = idx & 15;
        *(uint4*)&Bs[r * 136 + ch * 8] = *(const uint4*)&wt[(size_t)r * 128 + ch * 8];
    }
    __syncthreads();

    f32x4 acc[8] = {};
    #pragma unroll
    for (int ks = 0; ks < 4; ks++) {
        bf16x8 a = *(bf16x8*)&As[(w * 16 + c) * 136 + (ks * 4 + q) * 8];
        #pragma unroll
        for (int tl = 0; tl < 8; tl++) {
            bf16x8 b = *(bf16x8*)&Bs[(tl * 16 + c) * 136 + (ks * 4 + q) * 8];
            acc[tl] = __builtin_amdgcn_mfma_f32_16x16x32_bf16(a, b, acc[tl], 0, 0, 0);
        }
    }

    #pragma unroll
    for (int reg = 0; reg < 4; reg++) {
        int grow = row0 + w * 16 + q * 4 + reg;
        if (grow < M) {
            #pragma unroll
            for (int tl = 0; tl < 8; tl++)
                hb[(size_t)grow * 128 + tl * 16 + c] = f2bf(acc[tl][reg]);
        }
    }

    float as_[8], ad_[8];
    #pragma unroll
    for (int tl = 0; tl < 8; tl++) { as_[tl] = asrc[tl * 16 + c]; ad_[tl] = adst[tl * 16 + c]; }
    #pragma unroll
    for (int reg = 0; reg < 4; reg++) {
        float s0 = 0.f, s1 = 0.f, d0 = 0.f, d1 = 0.f;
        #pragma unroll
        for (int tl = 0; tl < 4; tl++) { s0 += acc[tl][reg] * as_[tl]; d0 += acc[tl][reg] * ad_[tl]; }
        #pragma unroll
        for (int tl = 4; tl < 8; tl++) { s1 += acc[tl][reg] * as_[tl]; d1 += acc[tl][reg] * ad_[tl]; }
        #pragma unroll
        for (int off = 1; off < 16; off <<= 1) {
            s0 += __shfl_xor(s0, off); s1 += __shfl_xor(s1, off);
            d0 += __shfl_xor(d0, off); d1 += __shfl_xor(d1, off);
        }
        int grow = row0 + w * 16 + q * 4 + reg;
        if (c == 0 && grow < M) {
            *(float2*)&als[(size_t)grow * 2] = make_float2(s0, s1);
            *(float2*)&ald[(size_t)grow * 2] = make_float2(d0, d1);
        }
    }
}

// ---------------- fused softmax + aggregation: wave per dst node ----------------
static __device__ __forceinline__ void acc8(float* acc, uint4 v, float a) {
    float2 p;
    p = bf2x2(v.x); acc[0] += a * p.x; acc[1] += a * p.y;
    p = bf2x2(v.y); acc[2] += a * p.x; acc[3] += a * p.y;
    p = bf2x2(v.z); acc[4] += a * p.x; acc[5] += a * p.y;
    p = bf2x2(v.w); acc[6] += a * p.x; acc[7] += a * p.y;
}

template <int MEAN>
static __device__ __forceinline__ void attnagg(
    const int* __restrict__ rowptr, const unsigned short* __restrict__ ssrc,
    const float* __restrict__ als, const float* __restrict__ ald,
    float* __restrict__ alpha, const unsigned short* __restrict__ hb,
    const float* __restrict__ bias, int Nn, float* __restrict__ out) {
    int gw = (blockIdx.x * blockDim.x + threadIdx.x) >> 6;
    if (gw >= Nn) return;
    int lane = threadIdx.x & 63;
    int sub = lane >> 4, c = lane & 15, head = c >> 3;
    int beg = rowptr[gw], end = rowptr[gw + 1];
    int deg = end - beg;
    float2 dv = *(const float2*)&ald[(size_t)gw * 2];
    float acc[8] = {};

    if (deg <= 64) {
        bool on = lane < deg;
        int eidx = beg + (on ? lane : 0);
        int sreg = (int)ssrc[eidx];
        float2 av = *(const float2*)&als[(size_t)sreg * 2];
        float v0 = av.x + dv.x; v0 = v0 > 0.f ? v0 : NEG_SLOPE * v0;
        float v1 = av.y + dv.y; v1 = v1 > 0.f ? v1 : NEG_SLOPE * v1;
        // post-BN logits: |v| << 88, exp safe without max-subtraction
        float p0 = on ? __expf(v0) : 0.f;
        float p1 = on ? __expf(v1) : 0.f;
        float t0 = p0, t1 = p1;
        #pragma unroll
        for (int off = 32; off; off >>= 1) {
            t0 += __shfl_xor(t0, off);
            t1 += __shfl_xor(t1, off);
        }
        __half2 hpk = __floats2half2_rn(p0 / t0, p1 / t1);
        unsigned pk = *(unsigned*)&hpk;

        // pass 2: wave-uniform groups of 4 slots; 4-group batches for MLP,
        // then 2-group predicated tail (no rounding to 16-slot multiples).
        int nit = (deg + 3) >> 2;
        int it = 0;
        for (; it + 4 <= nit; it += 4) {
            int s_[4]; float a_[4];
            #pragma unroll
            for (int u = 0; u < 4; u++) {
                int jj = (it + u) * 4 + sub;
                int ls = jj & 63;
                s_[u] = __shfl(sreg, ls);
                unsigned pw = (unsigned)__shfl(pk, ls);
                a_[u] = (jj < deg) ? halfsel(pw, head) : 0.f;
            }
            #pragma unroll
            for (int u = 0; u < 4; u++) {
                uint4 v = *(const uint4*)&hb[(size_t)s_[u] * 128 + c * 8];
                acc8(acc, v, a_[u]);
            }
        }
        for (; it < nit; it += 2) {
            int s_[2]; float a_[2];
            #pragma unroll
            for (int u = 0; u < 2; u++) {
                int jj = (it + u) * 4 + sub;
                int ls = jj & 63;
                s_[u] = __shfl(sreg, ls);
                unsigned pw = (unsigned)__shfl(pk, ls);
                a_[u] = (jj < deg) ? halfsel(pw, head) : 0.f;
            }
            #pragma unroll
            for (int u = 0; u < 2; u++) {
                uint4 v = *(const uint4*)&hb[(size_t)s_[u] * 128 + c * 8];
                acc8(acc, v, a_[u]);
            }
        }
    } else {
        // fallback (deg > 64): alpha via global buffer, with max-subtract
        float d0 = dv.x, d1 = dv.y;
        float m0 = -1e30f, m1 = -1e30f;
        for (int e = beg + lane; e < end; e += 64) {
            int s = (int)ssrc[e];
            float v0 = als[s * 2] + d0;     v0 = v0 > 0.f ? v0 : NEG_SLOPE * v0;
            float v1 = als[s * 2 + 1] + d1; v1 = v1 > 0.f ? v1 : NEG_SLOPE * v1;
            m0 = fmaxf(m0, v0); m1 = fmaxf(m1, v1);
        }
        #pragma unroll
        for (int off = 32; off; off >>= 1) {
            m0 = fmaxf(m0, __shfl_xor(m0, off));
            m1 = fmaxf(m1, __shfl_xor(m1, off));
        }
        float t0 = 0.f, t1 = 0.f;
        for (int e = beg + lane; e < end; e += 64) {
            int s = (int)ssrc[e];
            float v0 = als[s * 2] + d0;     v0 = v0 > 0.f ? v0 : NEG_SLOPE * v0;
            float v1 = als[s * 2 + 1] + d1; v1 = v1 > 0.f ? v1 : NEG_SLOPE * v1;
            float p0 = __expf(v0 - m0), p1 = __expf(v1 - m1);
            alpha[e * 2] = p0; alpha[e * 2 + 1] = p1;
            t0 += p0; t1 += p1;
        }
        #pragma unroll
        for (int off = 32; off; off >>= 1) {
            t0 += __shfl_xor(t0, off);
            t1 += __shfl_xor(t1, off);
        }
        float i0 = 1.f / t0, i1 = 1.f / t1;
        for (int e = beg + sub; e < end; e += 4) {
            int s = (int)ssrc[e];
            float a = (head ? alpha[(size_t)e * 2 + 1] * i1 : alpha[(size_t)e * 2] * i0);
            uint4 v = *(const uint4*)&hb[(size_t)s * 128 + c * 8];
            acc8(acc, v, a);
        }
    }

    #pragma unroll
    for (int j2 = 0; j2 < 8; j2++) {
        acc[j2] += __shfl_xor(acc[j2], 16);
        acc[j2] += __shfl_xor(acc[j2], 32);
        if (MEAN) acc[j2] += __shfl_xor(acc[j2], 8);
    }
    if (MEAN) {
        if (sub == 0 && c < 8) {
            float4 b0 = *(const float4*)&bias[c * 8];
            float4 b1 = *(const float4*)&bias[c * 8 + 4];
            float4 o0 = make_float4(0.5f * acc[0] + b0.x, 0.5f * acc[1] + b0.y, 0.5f * acc[2] + b0.z, 0.5f * acc[3] + b0.w);
            float4 o1 = make_float4(0.5f * acc[4] + b1.x, 0.5f * acc[5] + b1.y, 0.5f * acc[6] + b1.z, 0.5f * acc[7] + b1.w);
            *(float4*)&out[(size_t)gw * 64 + c * 8] = o0;
            *(float4*)&out[(size_t)gw * 64 + c * 8 + 4] = o1;
        }
    } else {
        if (sub == 0) {
            float4 b0 = *(const float4*)&bias[c * 8];
            float4 b1 = *(const float4*)&bias[c * 8 + 4];
            float4 o0 = make_float4(acc[0] + b0.x, acc[1] + b0.y, acc[2] + b0.z, acc[3] + b0.w);
            float4 o1 = make_float4(acc[4] + b1.x, acc[5] + b1.y, acc[6] + b1.z, acc[7] + b1.w);
            *(float4*)&out[(size_t)gw * 128 + c * 8] = o0;
            *(float4*)&out[(size_t)gw * 128 + c * 8 + 4] = o1;
        }
    }
}

__global__ __launch_bounds__(256) void k_attnagg1(const int* __restrict__ rowptr, const unsigned short* __restrict__ ssrc,
                                                  const float* __restrict__ als, const float* __restrict__ ald,
                                                  float* __restrict__ alpha, const unsigned short* __restrict__ hb,
                                                  const float* __restrict__ bias, int Nn, float* __restrict__ out) {
    attnagg<0>(rowptr, ssrc, als, ald, alpha, hb, bias, Nn, out);
}

__global__ __launch_bounds__(256) void k_attnagg2(const int* __restrict__ rowptr, const unsigned short* __restrict__ ssrc,
                                                  const float* __restrict__ als, const float* __restrict__ ald,
                                                  float* __restrict__ alpha, const unsigned short* __restrict__ hb,
                                                  const float* __restrict__ bias, int Nn, float* __restrict__ out) {
    attnagg<1>(rowptr, ssrc, als, ald, alpha, hb, bias, Nn, out);
}

// ---------------- final GEMM [M,64] @ [64,40] + bias, BN affine + ELU fused on A ----------------
__global__ __launch_bounds__(128) void k_gemmf(const float* __restrict__ A, const float* __restrict__ Wf,
                                               const float* __restrict__ bf, const float* __restrict__ st,
                                               int M, float* __restrict__ out) {
    __shared__ float As[128 * 65];
    __shared__ float Bs[64 * 40];
    int t = threadIdx.x;
    int row0 = blockIdx.x * 128;
    for (int i = t; i < 64 * 40; i += 128) Bs[i] = Wf[i];
    for (int i = t; i < 128 * 64; i += 128) {
        int r = i >> 6, k = i & 63;
        int gr = row0 + r;
        float v = 0.f;
        if (gr < M) {
            v = A[(size_t)gr * 64 + k] * st[k] + st[64 + k];
            v = v > 0.f ? v : expm1f(v);
        }
        As[r * 65 + k] = v;
    }
    __syncthreads();
    int cg = t & 3, rg = t >> 2;
    float acc[4][10] = {};
    for (int k = 0; k < 64; k++) {
        float b[10];
        #pragma unroll
        for (int j = 0; j < 10; j++) b[j] = Bs[k * 40 + cg * 10 + j];
        #pragma unroll
        for (int r = 0; r < 4; r++) {
            float a = As[(rg * 4 + r) * 65 + k];
            #pragma unroll
            for (int j = 0; j < 10; j++) acc[r][j] += a * b[j];
        }
    }
    for (int r = 0; r < 4; r++) {
        int gr = row0 + rg * 4 + r;
        if (gr < M) {
            #pragma unroll
            for (int j = 0; j < 10; j++) out[(size_t)gr * 40 + cg * 10 + j] = acc[r][j] + bf[cg * 10 + j];
        }
    }
}

extern "C" void kernel_launch(void* const* d_in, const int* in_sizes, int n_in,
                              void* d_out, int out_size, void* d_ws, size_t ws_size,
                              hipStream_t stream) {
    const float* x     = (const float*)d_in[0];
    const int*   ei    = (const int*)d_in[1];
    const float* bn0_g = (const float*)d_in[2];
    const float* bn0_b = (const float*)d_in[3];
    const float* W1    = (const float*)d_in[4];
    const float* a1s   = (const float*)d_in[5];
    const float* a1d   = (const float*)d_in[6];
    const float* b1    = (const float*)d_in[7];
    const float* bn1_g = (const float*)d_in[8];
    const float* bn1_b = (const float*)d_in[9];
    const float* W2    = (const float*)d_in[10];
    const float* a2s   = (const float*)d_in[11];
    const float* a2d   = (const float*)d_in[12];
    const float* b2    = (const float*)d_in[13];
    const float* bn2_g = (const float*)d_in[14];
    const float* bn2_b = (const float*)d_in[15];
    const float* Wf    = (const float*)d_in[16];
    const float* bf    = (const float*)d_in[17];
    float* out = (float*)d_out;

    const int N  = in_sizes[0] / 128;   // 50000 < 65536: u16 ssrc/rank valid
    const int E  = in_sizes[1] / 2;
    const int ET = E + N;

    char* ws = (char*)d_ws;
    size_t off = 0;
    auto alloc = [&](size_t bytes) -> char* {
        char* p = ws + off;
        off = (off + bytes + 255) & ~(size_t)255;
        return p;
    };
    int*   cnt    = (int*)alloc((size_t)N * 4);
    int*   rowptr = (int*)alloc((size_t)(N + 1) * 4);
    unsigned short* ssrc = (unsigned short*)alloc((size_t)ET * 2);
    float* abuf   = (float*)alloc((size_t)N * 128 * 4);
    unsigned short* hb  = (unsigned short*)alloc((size_t)N * 128 * 2);
    unsigned short* wt1 = (unsigned short*)alloc((size_t)128 * 128 * 2);
    unsigned short* wt2 = (unsigned short*)alloc((size_t)128 * 128 * 2);
    float* alpha  = (float*)alloc((size_t)ET * 2 * 4);   // deg>64 fallback only
    float* als    = (float*)alloc((size_t)N * 2 * 4);
    float* ald    = (float*)alloc((size_t)N * 2 * 4);
    int*   part   = (int*)alloc(1024 * 4);
    float* sums   = (float*)alloc(640 * 4);      // BN0:0, BN1:+256, BN2:+512
    float* st     = (float*)alloc(256 * 4);
    // alias: rank (u16) lives k_rank -> k_fill2; hb first written at k_mfma
    unsigned short* rank = (unsigned short*)hb;

    const int tb = 256;
    const int rgrid = (E + tb - 1) / tb;
    const int fgrid = (ET + tb - 1) / tb;
    const int wgrid = ((size_t)N * 64 + tb - 1) / tb;
    const int ggrid = (N + 63) / 64;
    const int nscan = (N + 1023) / 1024;
    const int bgrid = (N + 255) / 256;

    // CSR build
    hipMemsetAsync(cnt, 0, (size_t)N * 4, stream);
    hipMemsetAsync(sums, 0, 640 * 4, stream);
    k_rank<<<rgrid, tb, 0, stream>>>(ei, E, cnt, rank);
    k_part<<<nscan, 1024, 0, stream>>>(cnt, N, part);
    k_scan2<<<nscan, 1024, 0, stream>>>(cnt, N, nscan, part, rowptr);
    k_fill2<<<fgrid, tb, 0, stream>>>(ei, rank, rowptr, E, N, ssrc);

    // weights
    k_wt2<<<64, tb, 0, stream>>>(W1, W2, wt1, wt2);

    // BN0
    k_bnstat2<128><<<bgrid, 256, 0, stream>>>(x, N, 256, sums);
    k_bnfin<<<1, 128, 0, stream>>>(sums, N, 128, bn0_g, bn0_b, st);

    // layer 1 (BN0 affine fused into GEMM A staging)
    k_mfma<<<ggrid, tb, 0, stream>>>(x, wt1, st, 0, a1s, a1d, N, hb, als, ald);
    k_attnagg1<<<wgrid, tb, 0, stream>>>(rowptr, ssrc, als, ald, alpha, hb, b1, N, abuf);

    // BN1
    k_bnstat2<128><<<bgrid, 256, 0, stream>>>(abuf, N, 256, sums + 256);
    k_bnfin<<<1, 128, 0, stream>>>(sums + 256, N, 128, bn1_g, bn1_b, st);

    // layer 2 (BN1 affine + ELU fused into GEMM A staging)
    k_mfma<<<ggrid, tb, 0, stream>>>(abuf, wt2, st, 1, a2s, a2d, N, hb, als, ald);
    k_attnagg2<<<wgrid, tb, 0, stream>>>(rowptr, ssrc, als, ald, alpha, hb, b2, N, abuf);

    // BN2
    k_bnstat2<64><<<bgrid, 256, 0, stream>>>(abuf, N, 256, sums + 512);
    k_bnfin<<<1, 64, 0, stream>>>(sums + 512, N, 64, bn2_g, bn2_b, st);

    // final linear
    k_gemmf<<<(N + 127) / 128, 128, 0, stream>>>(abuf, Wf, bf, st, N, out);
}